// Round 4
// baseline (710.132 us; speedup 1.0000x reference)
//
#include <hip/hip_runtime.h>
#include <hip/hip_bf16.h>

// NeuralODE RK4, bf16 MFMA persistent kernel, swapped-operand, 4-wave WGs.
// BS=1024, ZDIM=HID=256, TLEN=128 -> 127 steps x 4 stages = 508 f-evals.
//
// 64 WGs x 256 threads (4 waves, 1/SIMD). WG owns 16 batch rows; wave wv owns
// output cols [64wv, 64wv+64) (4 n-tiles of 16). Weights in VGPRs (B-frag
// layout, 256 VGPR/wave), loaded once. Rationale: per-stage LDS read volume =
// #waves x 16KB (every wave re-reads the full 16x256 state for both GEMMs) and
// R3 (8 waves) was LDS-BW-bound at 128KB/stage; 4 waves halves that while
// keeping per-SIMD MFMA work identical (32 MFMA/stage/SIMD).
//
// Swapped trick: S = z@W computed as S^T = W^T @ z^T (weights = A operand).
// C/D layout then has col(lane&15) = batch row m = the m of the frags the
// lane loads next -> LDS round-trip is per-m contiguous: packed b64 writes,
// b128 frag reads.

#define BS   1024
#define ZDIM 256
#define TLEN 128
#define ROWSTRIDE 264   // u16 units; 528B row stride (16B aligned, bank offset 4/row)

typedef short v8s __attribute__((ext_vector_type(8)));
typedef float v4f __attribute__((ext_vector_type(4)));

static __device__ __forceinline__ ushort f2bf_rne(float x) {
    union { float f; unsigned u; } v; v.f = x;
    unsigned r = v.u + 0x7FFFu + ((v.u >> 16) & 1u);
    return (ushort)(r >> 16);
}

static __device__ __forceinline__ unsigned pk2(float a, float b) {
    union { __hip_bfloat162 h; unsigned u; } cv;
    cv.h = __float22bfloat162_rn(make_float2(a, b));
    return cv.u;
}

static __device__ __forceinline__ float fast_tanh(float x) {
    // tanh(x) = 1 - 2/(exp2(2x*log2e)+1); v_exp + v_rcp
    float e = __builtin_amdgcn_exp2f(2.88539008177793f * x);
    float r = __builtin_amdgcn_rcpf(e + 1.0f);
    return 1.0f - 2.0f * r;
}

__global__ __launch_bounds__(256, 1)
void ode_mfma_kernel(const float* __restrict__ z0,
                     const float* __restrict__ t,
                     const float* __restrict__ W1,
                     const float* __restrict__ b1,
                     const float* __restrict__ W2,
                     const float* __restrict__ b2,
                     float* __restrict__ out)
{
    __shared__ ushort zbuf[16 * ROWSTRIDE];
    __shared__ ushort hbuf[16 * ROWSTRIDE];
    __shared__ float  tsh[TLEN];

    const int tid  = threadIdx.x;
    const int wv   = tid >> 6;        // 0..3
    const int lane = tid & 63;
    const int q    = lane >> 4;       // 0..3
    const int ln   = lane & 15;       // = batch row m within tile
    const int rowbase = blockIdx.x * 16;

    if (tid < TLEN) tsh[tid] = t[tid];

    // ---- one-time: weights -> registers, B-frag layout ----
    // frag[ct][ks]: lane holds W[k = 32ks + 8q + j][c = 64wv + 16ct + ln]
    v8s w1f[4][8], w2f[4][8];
    #pragma unroll
    for (int ct = 0; ct < 4; ++ct) {
        const int c = wv * 64 + ct * 16 + ln;
        #pragma unroll
        for (int ks = 0; ks < 8; ++ks) {
            v8s a, b;
            #pragma unroll
            for (int j = 0; j < 8; ++j) {
                const int k = ks * 32 + q * 8 + j;
                a[j] = (short)f2bf_rne(W1[k * ZDIM + c]);
                b[j] = (short)f2bf_rne(W2[k * ZDIM + c]);
            }
            w1f[ct][ks] = a;
            w2f[ct][ks] = b;
        }
    }

    // biases in C'-layout: value row (c = 64wv + 16ct + 4q + r)
    v4f b1f[4], b2f[4];
    #pragma unroll
    for (int ct = 0; ct < 4; ++ct)
        #pragma unroll
        for (int r = 0; r < 4; ++r) {
            b1f[ct][r] = b1[wv * 64 + ct * 16 + q * 4 + r];
            b2f[ct][r] = b2[wv * 64 + ct * 16 + q * 4 + r];
        }

    // LDS offsets (u16 units)
    const int rdbase = ln * ROWSTRIDE + q * 8;            // + 32*ks : b128 reads
    const int wrbase = ln * ROWSTRIDE + wv * 64 + q * 4;  // + 16*ct : b64 writes

    // ---- initial state ----
    float zloc[4][4];   // z[m=ln][c = 64wv+16ct+4q+r]
    #pragma unroll
    for (int ct = 0; ct < 4; ++ct) {
        #pragma unroll
        for (int r = 0; r < 4; ++r)
            zloc[ct][r] = z0[(rowbase + ln) * ZDIM + wv * 64 + ct * 16 + q * 4 + r];
        uint2 p; p.x = pk2(zloc[ct][0], zloc[ct][1]); p.y = pk2(zloc[ct][2], zloc[ct][3]);
        *(uint2*)&zbuf[wrbase + ct * 16] = p;
    }
    __syncthreads();

    float kacc[4][4];

    #pragma unroll 1
    for (int step = 0; step < TLEN - 1; ++step) {
        const float h = tsh[step + 1] - tsh[step];

        #pragma unroll
        for (int stage = 0; stage < 4; ++stage) {
            // ---- GEMM1: S^T = W1^T z^T + b1 ----
            v4f acc[4];
            #pragma unroll
            for (int ct = 0; ct < 4; ++ct) acc[ct] = b1f[ct];
            #pragma unroll
            for (int ks = 0; ks < 8; ++ks) {
                const v8s zf = *(const v8s*)&zbuf[rdbase + ks * 32];
                #pragma unroll
                for (int ct = 0; ct < 4; ++ct)
                    acc[ct] = __builtin_amdgcn_mfma_f32_16x16x32_bf16(
                        w1f[ct][ks], zf, acc[ct], 0, 0, 0);
            }
            // tanh -> hbuf (packed b64 per ct)
            #pragma unroll
            for (int ct = 0; ct < 4; ++ct) {
                uint2 p;
                p.x = pk2(fast_tanh(acc[ct][0]), fast_tanh(acc[ct][1]));
                p.y = pk2(fast_tanh(acc[ct][2]), fast_tanh(acc[ct][3]));
                *(uint2*)&hbuf[wrbase + ct * 16] = p;
            }
            __syncthreads();

            // ---- GEMM2: f^T = W2^T h^T + b2 ----
            v4f fac[4];
            #pragma unroll
            for (int ct = 0; ct < 4; ++ct) fac[ct] = b2f[ct];
            #pragma unroll
            for (int ks = 0; ks < 8; ++ks) {
                const v8s hf = *(const v8s*)&hbuf[rdbase + ks * 32];
                #pragma unroll
                for (int ct = 0; ct < 4; ++ct)
                    fac[ct] = __builtin_amdgcn_mfma_f32_16x16x32_bf16(
                        w2f[ct][ks], hf, fac[ct], 0, 0, 0);
            }

            // ---- RK4 epilogue ----
            #pragma unroll
            for (int ct = 0; ct < 4; ++ct) {
                float zn[4];
                #pragma unroll
                for (int r = 0; r < 4; ++r) {
                    const float f = fac[ct][r];
                    if (stage == 0) {
                        kacc[ct][r] = f;
                        zn[r] = zloc[ct][r] + 0.5f * h * f;
                    } else if (stage == 1) {
                        kacc[ct][r] += 2.0f * f;
                        zn[r] = zloc[ct][r] + 0.5f * h * f;
                    } else if (stage == 2) {
                        kacc[ct][r] += 2.0f * f;
                        zn[r] = zloc[ct][r] + h * f;
                    } else {
                        kacc[ct][r] += f;
                        zloc[ct][r] += (h * (1.0f / 6.0f)) * kacc[ct][r];
                        zn[r] = zloc[ct][r];
                    }
                }
                uint2 p; p.x = pk2(zn[0], zn[1]); p.y = pk2(zn[2], zn[3]);
                *(uint2*)&zbuf[wrbase + ct * 16] = p;
            }
            __syncthreads();
        }
    }

    // ---- final store ----
    #pragma unroll
    for (int ct = 0; ct < 4; ++ct)
        #pragma unroll
        for (int r = 0; r < 4; ++r)
            out[(rowbase + ln) * ZDIM + wv * 64 + ct * 16 + q * 4 + r] = zloc[ct][r];
}

extern "C" void kernel_launch(void* const* d_in, const int* in_sizes, int n_in,
                              void* d_out, int out_size, void* d_ws, size_t ws_size,
                              hipStream_t stream) {
    const float* z0 = (const float*)d_in[0];
    const float* t  = (const float*)d_in[1];
    const float* W1 = (const float*)d_in[2];
    const float* b1 = (const float*)d_in[3];
    const float* W2 = (const float*)d_in[4];
    const float* b2 = (const float*)d_in[5];
    float* out = (float*)d_out;

    dim3 grid(BS / 16);    // 64 workgroups, 16 batch rows each
    dim3 block(256);       // 4 waves, 1 per SIMD
    hipLaunchKernelGGL(ode_mfma_kernel, grid, block, 0, stream,
                       z0, t, W1, b1, W2, b2, out);
}

// Round 5
// 559.452 us; speedup vs baseline: 1.2693x; 1.2693x over previous
//
#include <hip/hip_runtime.h>
#include <hip/hip_bf16.h>

// NeuralODE RK4, bf16 MFMA persistent kernel, swapped-operand, M=4 broadcast.
// BS=1024, ZDIM=HID=256, TLEN=128 -> 127 steps x 4 stages = 508 f-evals.
//
// 256 WGs x 512 threads (8 waves, 2/SIMD -- R4 proved 1/SIMD is latency-
// crippled). Each WG owns only M=4 batch rows; MFMA N=16 rows are the 4 real
// rows replicated 4x via row-wrap (ln & 3) on the LDS fragment reads: the
// b128 read then presents only 4 distinct addresses (rest broadcast), spread
// over distinct bank groups by the 264-u16 row stride -> near-zero conflicts
// and minimum LDS data cycles. Lanes ln>=4 compute bit-identical duplicates
// and are predicated off all LDS/global writes.
//
// Swapped trick (unchanged): S = z@W as S^T = W^T@z^T (weights = MFMA A
// operand, register-resident B-frag layout, 128 VGPRs/wave). C/D col(lane&15)
// = batch row; per-m-contiguous LDS round-trip (b64 writes / b128 reads).

#define BS   1024
#define ZDIM 256
#define TLEN 128
#define ROWSTRIDE 264   // u16; 528 B: 16B-aligned, shifts bank group by 1/row

typedef short v8s __attribute__((ext_vector_type(8)));
typedef float v4f __attribute__((ext_vector_type(4)));

static __device__ __forceinline__ ushort f2bf_rne(float x) {
    union { float f; unsigned u; } v; v.f = x;
    unsigned r = v.u + 0x7FFFu + ((v.u >> 16) & 1u);
    return (ushort)(r >> 16);
}

static __device__ __forceinline__ unsigned pk2(float a, float b) {
    union { __hip_bfloat162 h; unsigned u; } cv;
    cv.h = __float22bfloat162_rn(make_float2(a, b));
    return cv.u;
}

static __device__ __forceinline__ float fast_tanh(float x) {
    // tanh(x) = 1 - 2/(exp2(2x*log2e)+1); v_exp + v_rcp
    float e = __builtin_amdgcn_exp2f(2.88539008177793f * x);
    float r = __builtin_amdgcn_rcpf(e + 1.0f);
    return 1.0f - 2.0f * r;
}

__global__ __launch_bounds__(512, 1)
void ode_mfma_kernel(const float* __restrict__ z0,
                     const float* __restrict__ t,
                     const float* __restrict__ W1,
                     const float* __restrict__ b1,
                     const float* __restrict__ W2,
                     const float* __restrict__ b2,
                     float* __restrict__ out)
{
    __shared__ ushort zbuf[4 * ROWSTRIDE];   // 4 real rows only
    __shared__ ushort hbuf[4 * ROWSTRIDE];
    __shared__ float  tsh[TLEN];

    const int tid  = threadIdx.x;
    const int wv   = tid >> 6;        // 0..7
    const int lane = tid & 63;
    const int q    = lane >> 4;       // 0..3
    const int ln   = lane & 15;       // MFMA n-index (batch row, wrapped)
    const int rho  = ln & 3;          // real row 0..3
    const bool writer = (ln < 4);     // predicate for all writes
    const int rowbase = blockIdx.x * 4;

    if (tid < TLEN) tsh[tid] = t[tid];

    // ---- one-time: weights -> registers, B-frag layout ----
    // frag[ct][ks]: lane holds W[k = 32ks + 8q + j][c = 32wv + 16ct + ln]
    v8s w1f[2][8], w2f[2][8];
    #pragma unroll
    for (int ct = 0; ct < 2; ++ct) {
        const int c = wv * 32 + ct * 16 + ln;
        #pragma unroll
        for (int ks = 0; ks < 8; ++ks) {
            v8s a, b;
            #pragma unroll
            for (int j = 0; j < 8; ++j) {
                const int k = ks * 32 + q * 8 + j;
                a[j] = (short)f2bf_rne(W1[k * ZDIM + c]);
                b[j] = (short)f2bf_rne(W2[k * ZDIM + c]);
            }
            w1f[ct][ks] = a;
            w2f[ct][ks] = b;
        }
    }

    // biases in C'-layout: value row = weight col c = 32wv + 16ct + 4q + r
    v4f b1f[2], b2f[2];
    #pragma unroll
    for (int ct = 0; ct < 2; ++ct)
        #pragma unroll
        for (int r = 0; r < 4; ++r) {
            b1f[ct][r] = b1[wv * 32 + ct * 16 + q * 4 + r];
            b2f[ct][r] = b2[wv * 32 + ct * 16 + q * 4 + r];
        }

    // LDS offsets (u16 units); reads use wrapped row rho
    const int rdbase = rho * ROWSTRIDE + q * 8;           // + 32*ks : b128
    const int wrbase = ln  * ROWSTRIDE + wv * 32 + q * 4; // + 16*ct : b64 (ln<4)

    // ---- initial state (duplicate lanes load duplicate rows; harmless) ----
    float zloc[2][4];   // z[row rho][c = 32wv+16ct+4q+r]
    #pragma unroll
    for (int ct = 0; ct < 2; ++ct) {
        #pragma unroll
        for (int r = 0; r < 4; ++r)
            zloc[ct][r] = z0[(rowbase + rho) * ZDIM + wv * 32 + ct * 16 + q * 4 + r];
        if (writer) {
            uint2 p; p.x = pk2(zloc[ct][0], zloc[ct][1]); p.y = pk2(zloc[ct][2], zloc[ct][3]);
            *(uint2*)&zbuf[wrbase + ct * 16] = p;
        }
    }
    __syncthreads();

    float kacc[2][4];

    #pragma unroll 1
    for (int step = 0; step < TLEN - 1; ++step) {
        const float h = tsh[step + 1] - tsh[step];

        #pragma unroll
        for (int stage = 0; stage < 4; ++stage) {
            // ---- GEMM1: S^T = W1^T z^T + b1 ----
            v4f acc0 = b1f[0], acc1 = b1f[1];
            #pragma unroll
            for (int ks = 0; ks < 8; ++ks) {
                const v8s zf = *(const v8s*)&zbuf[rdbase + ks * 32];
                acc0 = __builtin_amdgcn_mfma_f32_16x16x32_bf16(w1f[0][ks], zf, acc0, 0, 0, 0);
                acc1 = __builtin_amdgcn_mfma_f32_16x16x32_bf16(w1f[1][ks], zf, acc1, 0, 0, 0);
            }
            // tanh -> hbuf (packed b64 per ct, writer lanes only)
            if (writer) {
                uint2 p0, p1;
                p0.x = pk2(fast_tanh(acc0[0]), fast_tanh(acc0[1]));
                p0.y = pk2(fast_tanh(acc0[2]), fast_tanh(acc0[3]));
                p1.x = pk2(fast_tanh(acc1[0]), fast_tanh(acc1[1]));
                p1.y = pk2(fast_tanh(acc1[2]), fast_tanh(acc1[3]));
                *(uint2*)&hbuf[wrbase]      = p0;
                *(uint2*)&hbuf[wrbase + 16] = p1;
            }
            __syncthreads();

            // ---- GEMM2: f^T = W2^T h^T + b2 ----
            v4f f0 = b2f[0], f1 = b2f[1];
            #pragma unroll
            for (int ks = 0; ks < 8; ++ks) {
                const v8s hf = *(const v8s*)&hbuf[rdbase + ks * 32];
                f0 = __builtin_amdgcn_mfma_f32_16x16x32_bf16(w2f[0][ks], hf, f0, 0, 0, 0);
                f1 = __builtin_amdgcn_mfma_f32_16x16x32_bf16(w2f[1][ks], hf, f1, 0, 0, 0);
            }

            // ---- RK4 epilogue (all lanes compute; writer lanes store) ----
            #pragma unroll
            for (int ct = 0; ct < 2; ++ct) {
                float zn[4];
                #pragma unroll
                for (int r = 0; r < 4; ++r) {
                    const float f = (ct == 0) ? f0[r] : f1[r];
                    if (stage == 0) {
                        kacc[ct][r] = f;
                        zn[r] = zloc[ct][r] + 0.5f * h * f;
                    } else if (stage == 1) {
                        kacc[ct][r] += 2.0f * f;
                        zn[r] = zloc[ct][r] + 0.5f * h * f;
                    } else if (stage == 2) {
                        kacc[ct][r] += 2.0f * f;
                        zn[r] = zloc[ct][r] + h * f;
                    } else {
                        kacc[ct][r] += f;
                        zloc[ct][r] += (h * (1.0f / 6.0f)) * kacc[ct][r];
                        zn[r] = zloc[ct][r];
                    }
                }
                if (writer) {
                    uint2 p; p.x = pk2(zn[0], zn[1]); p.y = pk2(zn[2], zn[3]);
                    *(uint2*)&zbuf[wrbase + ct * 16] = p;
                }
            }
            __syncthreads();
        }
    }

    // ---- final store (writer lanes only) ----
    if (writer) {
        #pragma unroll
        for (int ct = 0; ct < 2; ++ct)
            #pragma unroll
            for (int r = 0; r < 4; ++r)
                out[(rowbase + ln) * ZDIM + wv * 32 + ct * 16 + q * 4 + r] = zloc[ct][r];
    }
}

extern "C" void kernel_launch(void* const* d_in, const int* in_sizes, int n_in,
                              void* d_out, int out_size, void* d_ws, size_t ws_size,
                              hipStream_t stream) {
    const float* z0 = (const float*)d_in[0];
    const float* t  = (const float*)d_in[1];
    const float* W1 = (const float*)d_in[2];
    const float* b1 = (const float*)d_in[3];
    const float* W2 = (const float*)d_in[4];
    const float* b2 = (const float*)d_in[5];
    float* out = (float*)d_out;

    dim3 grid(BS / 4);     // 256 workgroups, 4 batch rows each -> all 256 CUs
    dim3 block(512);       // 8 waves, 2 per SIMD
    hipLaunchKernelGGL(ode_mfma_kernel, grid, block, 0, stream,
                       z0, t, W1, b1, W2, b2, out);
}